// Round 1
// 452.168 us; speedup vs baseline: 1.0020x; 1.0020x over previous
//
#include <hip/hip_runtime.h>
#include <math.h>

typedef float  f4v __attribute__((ext_vector_type(4)));
typedef short  s8v __attribute__((ext_vector_type(8)));
typedef int    i4v __attribute__((ext_vector_type(4)));

__device__ __forceinline__ float sigm(float x) { return 1.f / (1.f + expf(-x)); }
__device__ __forceinline__ unsigned short f2bf(float f) {
    unsigned int u = __float_as_uint(f);
    return (unsigned short)((u + 0x7FFF + ((u >> 16) & 1)) >> 16);   // RTNE
}
// packed f32x2 -> bf16x2 in ONE VALU op (lo = first arg)
__device__ __forceinline__ unsigned int cvt2(float lo, float hi) {
    unsigned int r;
    asm("v_cvt_pk_bf16_f32 %0, %1, %2" : "=v"(r) : "v"(lo), "v"(hi));
    return r;
}
__device__ __forceinline__ s8v pack8(float4 a, float4 b) {
    union { unsigned int u[4]; s8v v; } r;
    r.u[0] = cvt2(a.x, a.y); r.u[1] = cvt2(a.z, a.w);
    r.u[2] = cvt2(b.x, b.y); r.u[3] = cvt2(b.z, b.w);
    return r.v;
}

// ---------------- amax over Whh (for i8 quantization scale) ----------------
__global__ __launch_bounds__(256) void k_amax(const float* __restrict__ Whh,
                                              unsigned int* __restrict__ amax_bits) {
    int i = blockIdx.x * 256 + threadIdx.x;          // grid 1024 -> 262144
    float v = fabsf(Whh[i]);
#pragma unroll
    for (int o = 1; o < 64; o <<= 1) v = fmaxf(v, __shfl_xor(v, o));
    if ((threadIdx.x & 63) == 0) atomicMax(amax_bits, __float_as_uint(v));
}

// ---------------- prep: pack weights (bf16 GEMM layouts; Whh -> i8) ----------------
__global__ __launch_bounds__(256) void k_prep(const float* __restrict__ W2, const float* __restrict__ W3,
                                              const float* __restrict__ Wfc, const float* __restrict__ Wih,
                                              const float* __restrict__ W1, const float* __restrict__ Whh,
                                              const unsigned int* __restrict__ amax_bits,
                                              unsigned short* __restrict__ W2p, unsigned short* __restrict__ W3p,
                                              unsigned short* __restrict__ Wfcp, unsigned short* __restrict__ Wihp,
                                              unsigned short* __restrict__ W1p, signed char* __restrict__ Wq) {
    int i = blockIdx.x * 256 + threadIdx.x;
    if (i < 32768) {
        W2p[i] = f2bf(W2[i]);
    } else if (i < 98304) {
        int j = i - 32768;
        int co = j >> 10, r = j & 1023, ci = r >> 4, s = r & 15, ky = s >> 2, kx = s & 3;
        W3p[j] = (ky < 3 && kx < 3) ? f2bf(W3[((co * 64 + ci) * 3 + ky) * 3 + kx]) : (unsigned short)0;
    } else if (i < 1703936) {
        int j = i - 98304;
        Wfcp[j] = f2bf(Wfc[j]);
    } else if (i < 2228224) {
        int j = i - 1703936;
        int n = j >> 9, k = j & 511;
        Wihp[j] = f2bf(Wih[n * 517 + k]);
    } else if (i < 2234368) {
        int j = i - 2228224;
        W1p[j] = f2bf(W1[j] * (1.f / 255.f));
    } else if (i < 2496512) {
        int j = i - 2234368;
        float amax = __uint_as_float(amax_bits[0]);
        float s = 127.f / amax;
        int qv = (int)rintf(Whh[j] * s);
        qv = qv > 127 ? 127 : (qv < -127 ? -127 : qv);
        Wq[j] = (signed char)qv;                     // [1024][256] natural
    }
}

// ---------------- conv1 (MFMA): M=409600, N=32, K=192; 4 pixels/lane ----------------
// depth-1 software pipeline on the A loads: issue K-step k+1's 8 loads before step k's MFMAs.
__global__ __launch_bounds__(256) void k_conv1(const float* __restrict__ img,
                                               const unsigned short* __restrict__ Bw,
                                               const float* __restrict__ bias,
                                               unsigned short* __restrict__ out) {
    __shared__ unsigned short c1s[32][260];
    int lane = threadIdx.x & 63, w = threadIdx.x >> 6;
    int l15 = lane & 15, q = lane >> 4;
    int m0 = blockIdx.x * 256;
    const float* Ap[4];
#pragma unroll
    for (int mf = 0; mf < 4; ++mf) {
        int m = m0 + w * 64 + mf * 16 + l15;
        int im = m / 400, p = m - im * 400;
        int oy = p / 20, ox = p - oy * 20;
        Ap[mf] = img + im * 21168 + oy * 336 + ox * 4;
    }
    const unsigned short* Bp0 = Bw + l15 * 192 + q * 8;
    const unsigned short* Bp1 = Bw + (16 + l15) * 192 + q * 8;
    s8v bf0[6], bf1[6];
#pragma unroll
    for (int ks = 0; ks < 6; ++ks) {
        bf0[ks] = *(const s8v*)(Bp0 + ks * 32);
        bf1[ks] = *(const s8v*)(Bp1 + ks * 32);
    }
    int roffs[6];
#pragma unroll
    for (int ks = 0; ks < 6; ++ks) {
        int k0 = ks * 32 + q * 8;
        int c = k0 >> 6, ky = (k0 >> 3) & 7;
        roffs[ks] = c * 7056 + ky * 84;
    }
    f4v acc[8];
#pragma unroll
    for (int i = 0; i < 8; ++i) acc[i] = (f4v){0.f, 0.f, 0.f, 0.f};
    float4 ca[4], cb[4];
#pragma unroll
    for (int mf = 0; mf < 4; ++mf) {
        ca[mf] = *(const float4*)(Ap[mf] + roffs[0]);
        cb[mf] = *(const float4*)(Ap[mf] + roffs[0] + 4);
    }
#pragma unroll
    for (int ks = 0; ks < 6; ++ks) {
        float4 na[4], nb[4];
        if (ks < 5) {
#pragma unroll
            for (int mf = 0; mf < 4; ++mf) {
                na[mf] = *(const float4*)(Ap[mf] + roffs[ks + 1]);
                nb[mf] = *(const float4*)(Ap[mf] + roffs[ks + 1] + 4);
            }
        }
#pragma unroll
        for (int mf = 0; mf < 4; ++mf) {
            s8v ua = pack8(ca[mf], cb[mf]);
            acc[mf * 2 + 0] = __builtin_amdgcn_mfma_f32_16x16x32_bf16(ua, bf0[ks], acc[mf * 2 + 0], 0, 0, 0);
            acc[mf * 2 + 1] = __builtin_amdgcn_mfma_f32_16x16x32_bf16(ua, bf1[ks], acc[mf * 2 + 1], 0, 0, 0);
        }
        if (ks < 5) {
#pragma unroll
            for (int mf = 0; mf < 4; ++mf) { ca[mf] = na[mf]; cb[mf] = nb[mf]; }
        }
    }
#pragma unroll
    for (int nf = 0; nf < 2; ++nf) {
        int n = nf * 16 + l15;
        float b = bias[n];
#pragma unroll
        for (int mf = 0; mf < 4; ++mf) {
            int ml = w * 64 + mf * 16 + q * 4;
#pragma unroll
            for (int r = 0; r < 4; r += 2) {
                float v0 = acc[mf * 2 + nf][r] + b;     v0 = v0 > 0.f ? v0 : 0.f;
                float v1 = acc[mf * 2 + nf][r + 1] + b; v1 = v1 > 0.f ? v1 : 0.f;
                *(unsigned int*)&c1s[n][ml + r] = cvt2(v0, v1);
            }
        }
    }
    __syncthreads();
#pragma unroll
    for (int seg = 0; seg < 32; ++seg) {
        int flat = seg * 256 + threadIdx.x;
        int n = flat >> 8, ml = flat & 255;
        int m = m0 + ml;
        int im = m / 400, p = m - im * 400;
        out[(im * 32 + n) * 400 + p] = c1s[n][ml];
    }
}

// ---------------- conv2 (MFMA): M=82944, N=64, K=512; depth-1 pipelined loads ----------------
__global__ __launch_bounds__(256) void k_conv2(const unsigned short* __restrict__ A,
                                               const unsigned short* __restrict__ Bw,
                                               const float* __restrict__ bias,
                                               unsigned short* __restrict__ out) {
    __shared__ unsigned short c2s[64][136];
    int lane = threadIdx.x & 63, w = threadIdx.x >> 6;
    int l15 = lane & 15, q = lane >> 4;
    int m0 = blockIdx.x * 128;
    int ma = m0 + w * 32 + l15, mb = ma + 16;
    int ia = ma / 81, pa = ma - ia * 81; int oya = pa / 9, oxa = pa - oya * 9;
    int ib = mb / 81, pb = mb - ib * 81; int oyb = pb / 9, oxb = pb - oyb * 9;
    const unsigned short* Aa = A + ia * 12800 + oya * 40 + oxa * 2 + (q & 1) * 40;
    const unsigned short* Ab = A + ib * 12800 + oyb * 40 + oxb * 2 + (q & 1) * 40;
    int ci0 = q >> 1;
    const unsigned short* B0 = Bw + (l15) * 512 + q * 8;
    const unsigned short* B1 = Bw + (16 + l15) * 512 + q * 8;
    const unsigned short* B2 = Bw + (32 + l15) * 512 + q * 8;
    const unsigned short* B3 = Bw + (48 + l15) * 512 + q * 8;
    f4v acc[8];
#pragma unroll
    for (int i = 0; i < 8; ++i) acc[i] = (f4v){0.f, 0.f, 0.f, 0.f};
    union AU { unsigned int u[4]; s8v v; };
    const unsigned short* pa_ = Aa + ci0 * 400;
    const unsigned short* pb_ = Ab + ci0 * 400;
    AU ua, ub;
    ua.u[0] = *(const unsigned int*)(pa_);      ua.u[1] = *(const unsigned int*)(pa_ + 2);
    ua.u[2] = *(const unsigned int*)(pa_ + 20); ua.u[3] = *(const unsigned int*)(pa_ + 22);
    ub.u[0] = *(const unsigned int*)(pb_);      ub.u[1] = *(const unsigned int*)(pb_ + 2);
    ub.u[2] = *(const unsigned int*)(pb_ + 20); ub.u[3] = *(const unsigned int*)(pb_ + 22);
    s8v b0 = *(const s8v*)B0, b1 = *(const s8v*)B1, b2 = *(const s8v*)B2, b3 = *(const s8v*)B3;
    for (int c = 0; c < 16; ++c) {
        AU nua, nub; s8v nb0, nb1, nb2, nb3;
        if (c < 15) {
            pa_ += 800; pb_ += 800; B0 += 32; B1 += 32; B2 += 32; B3 += 32;
            nua.u[0] = *(const unsigned int*)(pa_);      nua.u[1] = *(const unsigned int*)(pa_ + 2);
            nua.u[2] = *(const unsigned int*)(pa_ + 20); nua.u[3] = *(const unsigned int*)(pa_ + 22);
            nub.u[0] = *(const unsigned int*)(pb_);      nub.u[1] = *(const unsigned int*)(pb_ + 2);
            nub.u[2] = *(const unsigned int*)(pb_ + 20); nub.u[3] = *(const unsigned int*)(pb_ + 22);
            nb0 = *(const s8v*)B0; nb1 = *(const s8v*)B1; nb2 = *(const s8v*)B2; nb3 = *(const s8v*)B3;
        }
        acc[0] = __builtin_amdgcn_mfma_f32_16x16x32_bf16(ua.v, b0, acc[0], 0, 0, 0);
        acc[1] = __builtin_amdgcn_mfma_f32_16x16x32_bf16(ua.v, b1, acc[1], 0, 0, 0);
        acc[2] = __builtin_amdgcn_mfma_f32_16x16x32_bf16(ua.v, b2, acc[2], 0, 0, 0);
        acc[3] = __builtin_amdgcn_mfma_f32_16x16x32_bf16(ua.v, b3, acc[3], 0, 0, 0);
        acc[4] = __builtin_amdgcn_mfma_f32_16x16x32_bf16(ub.v, b0, acc[4], 0, 0, 0);
        acc[5] = __builtin_amdgcn_mfma_f32_16x16x32_bf16(ub.v, b1, acc[5], 0, 0, 0);
        acc[6] = __builtin_amdgcn_mfma_f32_16x16x32_bf16(ub.v, b2, acc[6], 0, 0, 0);
        acc[7] = __builtin_amdgcn_mfma_f32_16x16x32_bf16(ub.v, b3, acc[7], 0, 0, 0);
        if (c < 15) { ua = nua; ub = nub; b0 = nb0; b1 = nb1; b2 = nb2; b3 = nb3; }
    }
#pragma unroll
    for (int nf = 0; nf < 4; ++nf) {
        int n = nf * 16 + l15;
        float b = bias[n];
#pragma unroll
        for (int mf = 0; mf < 2; ++mf) {
            int ml = w * 32 + mf * 16 + q * 4;
#pragma unroll
            for (int r = 0; r < 4; r += 2) {
                float v0 = acc[mf * 4 + nf][r] + b;     v0 = v0 > 0.f ? v0 : 0.f;
                float v1 = acc[mf * 4 + nf][r + 1] + b; v1 = v1 > 0.f ? v1 : 0.f;
                *(unsigned int*)&c2s[n][ml + r] = cvt2(v0, v1);
            }
        }
    }
    __syncthreads();
#pragma unroll
    for (int seg = 0; seg < 32; ++seg) {
        int flat = seg * 256 + threadIdx.x;
        int n = flat >> 7, ml = flat & 127;
        int m = m0 + ml;
        int im = m / 81, p = m - im * 81;
        out[im * 5184 + n * 81 + p] = c2s[n][ml];
    }
}

// ---------------- conv3 (MFMA): M=50176, N=64; depth-1 pipelined scalar A loads ----------------
__global__ __launch_bounds__(256) void k_conv3(const unsigned short* __restrict__ A,
                                               const unsigned short* __restrict__ Bw,
                                               const float* __restrict__ bias,
                                               unsigned short* __restrict__ out) {
    __shared__ unsigned short c3s[64][136];
    int lane = threadIdx.x & 63, w = threadIdx.x >> 6;
    int l15 = lane & 15, q = lane >> 4;
    int m0 = blockIdx.x * 128;
    int ma = m0 + w * 32 + l15, mb = ma + 16;
    int ia = ma / 49, pa = ma - ia * 49; int oya = pa / 7, oxa = pa - oya * 7;
    int ib = mb / 49, pb = mb - ib * 49; int oyb = pb / 7, oxb = pb - oyb * 7;
    int ky0 = (q & 1) * 2;
    int r0off = ky0 * 9;
    int r1off = (ky0 + 1 > 2 ? 2 : ky0 + 1) * 9;
    int zr = q & 1;
    const unsigned short* Aa = A + ia * 5184 + oya * 9 + oxa;
    const unsigned short* Ab = A + ib * 5184 + oyb * 9 + oxb;
    int ci0 = q >> 1;
    const unsigned short* B0 = Bw + (l15) * 1024 + q * 8;
    const unsigned short* B1 = Bw + (16 + l15) * 1024 + q * 8;
    const unsigned short* B2 = Bw + (32 + l15) * 1024 + q * 8;
    const unsigned short* B3 = Bw + (48 + l15) * 1024 + q * 8;
    f4v acc[8];
#pragma unroll
    for (int i = 0; i < 8; ++i) acc[i] = (f4v){0.f, 0.f, 0.f, 0.f};
    const unsigned short* pa_ = Aa + ci0 * 81;
    const unsigned short* pb_ = Ab + ci0 * 81;
    unsigned short ca_[6], cb_[6];
    ca_[0] = pa_[r0off]; ca_[1] = pa_[r0off + 1]; ca_[2] = pa_[r0off + 2];
    ca_[3] = pa_[r1off]; ca_[4] = pa_[r1off + 1]; ca_[5] = pa_[r1off + 2];
    cb_[0] = pb_[r0off]; cb_[1] = pb_[r0off + 1]; cb_[2] = pb_[r0off + 2];
    cb_[3] = pb_[r1off]; cb_[4] = pb_[r1off + 1]; cb_[5] = pb_[r1off + 2];
    s8v b0 = *(const s8v*)B0, b1 = *(const s8v*)B1, b2 = *(const s8v*)B2, b3 = *(const s8v*)B3;
    for (int c = 0; c < 32; ++c) {
        unsigned short na_[6], nb_[6]; s8v nb0, nb1, nb2, nb3;
        if (c < 31) {
            pa_ += 162; pb_ += 162; B0 += 32; B1 += 32; B2 += 32; B3 += 32;
            na_[0] = pa_[r0off]; na_[1] = pa_[r0off + 1]; na_[2] = pa_[r0off + 2];
            na_[3] = pa_[r1off]; na_[4] = pa_[r1off + 1]; na_[5] = pa_[r1off + 2];
            nb_[0] = pb_[r0off]; nb_[1] = pb_[r0off + 1]; nb_[2] = pb_[r0off + 2];
            nb_[3] = pb_[r1off]; nb_[4] = pb_[r1off + 1]; nb_[5] = pb_[r1off + 2];
            nb0 = *(const s8v*)B0; nb1 = *(const s8v*)B1; nb2 = *(const s8v*)B2; nb3 = *(const s8v*)B3;
        }
        s8v av, bv;
        av[0] = (short)ca_[0]; av[1] = (short)ca_[1]; av[2] = (short)ca_[2]; av[3] = 0;
        av[4] = zr ? (short)0 : (short)ca_[3];
        av[5] = zr ? (short)0 : (short)ca_[4];
        av[6] = zr ? (short)0 : (short)ca_[5];
        av[7] = 0;
        bv[0] = (short)cb_[0]; bv[1] = (short)cb_[1]; bv[2] = (short)cb_[2]; bv[3] = 0;
        bv[4] = zr ? (short)0 : (short)cb_[3];
        bv[5] = zr ? (short)0 : (short)cb_[4];
        bv[6] = zr ? (short)0 : (short)cb_[5];
        bv[7] = 0;
        acc[0] = __builtin_amdgcn_mfma_f32_16x16x32_bf16(av, b0, acc[0], 0, 0, 0);
        acc[1] = __builtin_amdgcn_mfma_f32_16x16x32_bf16(av, b1, acc[1], 0, 0, 0);
        acc[2] = __builtin_amdgcn_mfma_f32_16x16x32_bf16(av, b2, acc[2], 0, 0, 0);
        acc[3] = __builtin_amdgcn_mfma_f32_16x16x32_bf16(av, b3, acc[3], 0, 0, 0);
        acc[4] = __builtin_amdgcn_mfma_f32_16x16x32_bf16(bv, b0, acc[4], 0, 0, 0);
        acc[5] = __builtin_amdgcn_mfma_f32_16x16x32_bf16(bv, b1, acc[5], 0, 0, 0);
        acc[6] = __builtin_amdgcn_mfma_f32_16x16x32_bf16(bv, b2, acc[6], 0, 0, 0);
        acc[7] = __builtin_amdgcn_mfma_f32_16x16x32_bf16(bv, b3, acc[7], 0, 0, 0);
        if (c < 31) {
#pragma unroll
            for (int j = 0; j < 6; ++j) { ca_[j] = na_[j]; cb_[j] = nb_[j]; }
            b0 = nb0; b1 = nb1; b2 = nb2; b3 = nb3;
        }
    }
#pragma unroll
    for (int nf = 0; nf < 4; ++nf) {
        int n = nf * 16 + l15;
        float b = bias[n];
#pragma unroll
        for (int mf = 0; mf < 2; ++mf) {
            int ml = w * 32 + mf * 16 + q * 4;
#pragma unroll
            for (int r = 0; r < 4; r += 2) {
                float v0 = acc[mf * 4 + nf][r] + b;     v0 = v0 > 0.f ? v0 : 0.f;
                float v1 = acc[mf * 4 + nf][r + 1] + b; v1 = v1 > 0.f ? v1 : 0.f;
                *(unsigned int*)&c3s[n][ml + r] = cvt2(v0, v1);
            }
        }
    }
    __syncthreads();
#pragma unroll
    for (int seg = 0; seg < 32; ++seg) {
        int flat = seg * 256 + threadIdx.x;
        int n = flat >> 7, ml = flat & 127;
        int m = m0 + ml;
        int im = m / 49, p = m - im * 49;
        out[im * 3136 + n * 49 + p] = c3s[n][ml];
    }
}

// ---------------- FC (MFMA): depth-1 pipelined ----------------
__global__ __launch_bounds__(256) void k_fc(const unsigned short* __restrict__ A,
                                            const unsigned short* __restrict__ Bw,
                                            const float* __restrict__ bias,
                                            unsigned short* __restrict__ out) {
    int lane = threadIdx.x & 63, w = threadIdx.x >> 6;
    int l15 = lane & 15, q = lane >> 4;
    int m0 = blockIdx.x * 32 + (w & 1) * 16;
    int n0 = blockIdx.y * 64 + (w >> 1) * 32;
    const unsigned short* Ap = A + (m0 + l15) * 3136 + q * 8;
    const unsigned short* B0 = Bw + (n0 + l15) * 3136 + q * 8;
    const unsigned short* B1 = B0 + 16 * 3136;
    f4v acc0 = (f4v){0.f, 0.f, 0.f, 0.f}, acc1 = (f4v){0.f, 0.f, 0.f, 0.f};
    s8v av = *(const s8v*)Ap, b0 = *(const s8v*)B0, b1 = *(const s8v*)B1;
    for (int c = 0; c < 97; ++c) {
        Ap += 32; B0 += 32; B1 += 32;
        s8v nav = *(const s8v*)Ap, nb0 = *(const s8v*)B0, nb1 = *(const s8v*)B1;
        acc0 = __builtin_amdgcn_mfma_f32_16x16x32_bf16(av, b0, acc0, 0, 0, 0);
        acc1 = __builtin_amdgcn_mfma_f32_16x16x32_bf16(av, b1, acc1, 0, 0, 0);
        av = nav; b0 = nb0; b1 = nb1;
    }
    acc0 = __builtin_amdgcn_mfma_f32_16x16x32_bf16(av, b0, acc0, 0, 0, 0);
    acc1 = __builtin_amdgcn_mfma_f32_16x16x32_bf16(av, b1, acc1, 0, 0, 0);
    float bi0 = bias[n0 + l15], bi1 = bias[n0 + 16 + l15];
#pragma unroll
    for (int r = 0; r < 4; ++r) {
        int m = m0 + q * 4 + r;
        float v0 = acc0[r] + bi0; v0 = v0 > 0.f ? v0 : 0.f;
        float v1 = acc1[r] + bi1; v1 = v1 > 0.f ? v1 : 0.f;
        out[m * 512 + n0 + l15] = f2bf(v0);
        out[m * 512 + n0 + 16 + l15] = f2bf(v1);
    }
}

// ---------------- gx (MFMA) ----------------
__global__ __launch_bounds__(256) void k_gx(const unsigned short* __restrict__ A,
                                            const unsigned short* __restrict__ Bw,
                                            const float* __restrict__ Wih,
                                            const float* __restrict__ bih,
                                            const float* __restrict__ bhh,
                                            const int* __restrict__ act,
                                            float* __restrict__ out) {
    int lane = threadIdx.x & 63, w = threadIdx.x >> 6;
    int l15 = lane & 15, q = lane >> 4;
    int m0 = blockIdx.x * 32 + (w & 1) * 16;
    int n0 = blockIdx.y * 64 + (w >> 1) * 32;
    const unsigned short* Ap = A + (m0 + l15) * 512 + q * 8;
    const unsigned short* B0 = Bw + (n0 + l15) * 512 + q * 8;
    const unsigned short* B1 = B0 + 16 * 512;
    f4v acc0 = (f4v){0.f, 0.f, 0.f, 0.f}, acc1 = (f4v){0.f, 0.f, 0.f, 0.f};
    for (int c = 0; c < 16; ++c) {
        s8v av = *(const s8v*)Ap;
        s8v b0 = *(const s8v*)B0;
        s8v b1 = *(const s8v*)B1;
        Ap += 32; B0 += 32; B1 += 32;
        acc0 = __builtin_amdgcn_mfma_f32_16x16x32_bf16(av, b0, acc0, 0, 0, 0);
        acc1 = __builtin_amdgcn_mfma_f32_16x16x32_bf16(av, b1, acc1, 0, 0, 0);
    }
    int na = n0 + l15, nb = n0 + 16 + l15;
    float ca = bih[na] + bhh[na], cb_ = bih[nb] + bhh[nb];
#pragma unroll
    for (int r = 0; r < 4; ++r) {
        int m = m0 + q * 4 + r;
        int a = act[m];
        out[m * 1024 + na] = acc0[r] + Wih[na * 517 + 512 + a] + ca;
        out[m * 1024 + nb] = acc1[r] + Wih[nb * 517 + 512 + a] + cb_;
    }
}

// ---------------- fused LSTM, env-split: 32 wgs x 1 env, NO inter-wg communication ----------------
__global__ __launch_bounds__(1024) void k_lstm_all(const float* __restrict__ h0,
                                                   const float* __restrict__ c0,
                                                   const float* __restrict__ done,
                                                   const float* __restrict__ gx,
                                                   const signed char* __restrict__ Wq,
                                                   const unsigned int* __restrict__ amax_bits,
                                                   float* __restrict__ hs,
                                                   float* __restrict__ cb) {
    int b = blockIdx.x;
    int tid = threadIdx.x;
    int w = tid >> 6, lane = tid & 63;
    int l15 = lane & 15, q = lane >> 4;
    __shared__ float gbuf[1024];
    __shared__ float cst[256];
    __shared__ signed char hA[4][64][16];            // A-operand layout, only m=0 rows live

    i4v wfr[4][4];
    const signed char* wb = Wq + (w * 64 + l15) * 256 + q * 16;
#pragma unroll
    for (int s = 0; s < 4; ++s)
#pragma unroll
        for (int kf = 0; kf < 4; ++kf)
            wfr[s][kf] = *(const i4v*)(wb + s * 16 * 256 + kf * 64);
    float sw = __uint_as_float(amax_bits[0]) * (1.f / (127.f * 127.f));

    ((int*)hA)[tid] = 0;                             // zero all (dead rows stay 0)
    __syncthreads();
    if (tid < 256) {
        int u = tid;
        cst[u] = c0[b * 256 + u];
        float m0v = 1.f - done[b];
        float hv = h0[b * 256 + u] * m0v;
        hv = hv > 1.f ? 1.f : (hv < -1.f ? -1.f : hv);
        hA[u >> 6][((u >> 4) & 3) * 16][u & 15] = (signed char)(int)rintf(hv * 127.f);
    }
    __syncthreads();

    for (int t = 0; t < 32; ++t) {
        // prefetch gx for this step (consumed after the barrier -> latency hidden)
        float gxi = 0.f, gxf = 0.f, gxg = 0.f, gxo = 0.f, dcur = 0.f, dnxt = 0.f;
        if (tid < 256) {
            const float* gr = gx + (t * 32 + b) * 1024;
            gxi = gr[tid]; gxf = gr[256 + tid]; gxg = gr[512 + tid]; gxo = gr[768 + tid];
            dcur = done[t * 32 + b];
            dnxt = (t < 31) ? done[(t + 1) * 32 + b] : 1.f;
        }
        i4v acc[4];
#pragma unroll
        for (int s = 0; s < 4; ++s) acc[s] = (i4v){0, 0, 0, 0};
#pragma unroll
        for (int kf = 0; kf < 4; ++kf) {
            i4v a = *(const i4v*)&hA[kf][lane][0];
#pragma unroll
            for (int s = 0; s < 4; ++s)
                acc[s] = __builtin_amdgcn_mfma_i32_16x16x64_i8(a, wfr[s][kf], acc[s], 0, 0, 0);
        }
        if (q == 0) {                                // row 0 of C lives in reg 0 of lanes 0..15
#pragma unroll
            for (int s = 0; s < 4; ++s)
                gbuf[w * 64 + s * 16 + l15] = (float)acc[s][0];
        }
        __syncthreads();
        if (tid < 256) {
            int u = tid;
            float gi = gbuf[u] * sw + gxi;
            float gf = gbuf[256 + u] * sw + gxf;
            float gg = gbuf[512 + u] * sw + gxg;
            float go = gbuf[768 + u] * sw + gxo;
            float cm = cst[u] * (1.f - dcur);
            float cn = sigm(gf) * cm + sigm(gi) * tanhf(gg);
            float hn = sigm(go) * tanhf(cn);
            cst[u] = cn;
            hs[t * 8192 + b * 256 + u] = hn;
            float hv = hn * (1.f - dnxt);            // |h|<1; done in {0,1} -> exact
            hA[u >> 6][((u >> 4) & 3) * 16][u & 15] = (signed char)(int)rintf(hv * 127.f);
        }
        __syncthreads();
    }
    if (tid < 256) cb[b * 256 + tid] = cst[tid];
}

// ---------------- heads (fp32, unchanged) ----------------
__global__ __launch_bounds__(256) void k_heads(const float* __restrict__ hs,
                                               const float* __restrict__ cb,
                                               const float* __restrict__ Wp1, const float* __restrict__ bp1,
                                               const float* __restrict__ Wp2, const float* __restrict__ bp2,
                                               const float* __restrict__ Wv1, const float* __restrict__ bv1,
                                               const float* __restrict__ Wv2, const float* __restrict__ bv2,
                                               float* __restrict__ out) {
    int lane = threadIdx.x & 63;
    int m = blockIdx.x * 4 + (threadIdx.x >> 6);   // 0..1023
    const float4* hv = (const float4*)(hs + m * 256);
    const float4* wp = (const float4*)(Wp1 + lane * 256);
    const float4* wq = (const float4*)(Wv1 + lane * 256);
    float ap = 0.f, av = 0.f;
#pragma unroll 8
    for (int k = 0; k < 64; ++k) {
        float4 h4 = hv[k];
        float4 p4 = wp[k];
        float4 q4 = wq[k];
        ap += h4.x * p4.x + h4.y * p4.y + h4.z * p4.z + h4.w * p4.w;
        av += h4.x * q4.x + h4.y * q4.y + h4.z * q4.z + h4.w * q4.w;
    }
    float hp = tanhf(ap + bp1[lane]);
    float hq = tanhf(av + bv1[lane]);
#pragma unroll
    for (int j = 0; j < 5; ++j) {
        float s = hp * Wp2[j * 64 + lane];
        s += __shfl_xor(s, 1); s += __shfl_xor(s, 2); s += __shfl_xor(s, 4);
        s += __shfl_xor(s, 8); s += __shfl_xor(s, 16); s += __shfl_xor(s, 32);
        if (lane == 0) out[m * 5 + j] = s + bp2[j];
    }
    float s = hq * Wv2[lane];
    s += __shfl_xor(s, 1); s += __shfl_xor(s, 2); s += __shfl_xor(s, 4);
    s += __shfl_xor(s, 8); s += __shfl_xor(s, 16); s += __shfl_xor(s, 32);
    if (lane == 0) out[5120 + m] = s + bv2[0];

    int g = blockIdx.x * 256 + threadIdx.x;
    if (g < 8192) {
        out[6144 + g] = hs[31 * 8192 + g];          // hT
        out[6144 + 8192 + g] = cb[g];               // cT
    }
}

extern "C" void kernel_launch(void* const* d_in, const int* in_sizes, int n_in,
                              void* d_out, int out_size, void* d_ws, size_t ws_size,
                              hipStream_t stream) {
    const float* image = (const float*)d_in[0];
    const int*   act   = (const int*)d_in[1];
    const float* done  = (const float*)d_in[2];
    const float* h0    = (const float*)d_in[3];
    const float* c0    = (const float*)d_in[4];
    const float* W1    = (const float*)d_in[5];
    const float* b1    = (const float*)d_in[6];
    const float* W2    = (const float*)d_in[7];
    const float* b2    = (const float*)d_in[8];
    const float* W3    = (const float*)d_in[9];
    const float* b3    = (const float*)d_in[10];
    const float* Wfc   = (const float*)d_in[11];
    const float* bfc   = (const float*)d_in[12];
    const float* Wih   = (const float*)d_in[13];
    const float* Whh   = (const float*)d_in[14];
    const float* bih   = (const float*)d_in[15];
    const float* bhh   = (const float*)d_in[16];
    const float* Wp1   = (const float*)d_in[17];
    const float* bp1   = (const float*)d_in[18];
    const float* Wp2   = (const float*)d_in[19];
    const float* bp2   = (const float*)d_in[20];
    const float* Wv1   = (const float*)d_in[21];
    const float* bv1   = (const float*)d_in[22];
    const float* Wv2   = (const float*)d_in[23];
    const float* bv2   = (const float*)d_in[24];
    float* out = (float*)d_out;
    char* base = (char*)d_ws;

    // ---- workspace layout (bytes) ----
    unsigned short* a1   = (unsigned short*)(base);             // 26,214,400
    unsigned short* a2   = (unsigned short*)(base + 26214432);  // 10,616,832
    unsigned short* W2p  = (unsigned short*)(base + 36831328);
    unsigned short* W3p  = W2p + 32768;
    unsigned short* Wfcp = W2p + 98304;
    unsigned short* Wihp = W2p + 1703936;
    unsigned short* W1p  = (unsigned short*)(base + 41287776);  // 12,288
    unsigned int*   amax = (unsigned int*)(base + 41300064);    // 4 (+pad)
    signed char*    Wq   = (signed char*)(base + 41300096);     // 262,144
    unsigned short* a3   = (unsigned short*)(base);             // overlays dead a1
    unsigned short* feat = (unsigned short*)(base + 6422528);
    float* gx = (float*)(base + 7471104);
    float* hs = (float*)(base + 11665408);
    float* cb = (float*)(base + 12713984);

    hipMemsetAsync(amax, 0, 4, stream);
    k_amax<<<1024, 256, 0, stream>>>(Whh, amax);
    k_prep<<<9752, 256, 0, stream>>>(W2, W3, Wfc, Wih, W1, Whh, amax, W2p, W3p, Wfcp, Wihp, W1p, Wq);
    k_conv1<<<1600, 256, 0, stream>>>(image, W1p, b1, a1);
    k_conv2<<<648, 256, 0, stream>>>(a1, W2p, b2, a2);
    k_conv3<<<392, 256, 0, stream>>>(a2, W3p, b3, a3);
    k_fc<<<dim3(32, 8), 256, 0, stream>>>(a3, Wfcp, bfc, feat);
    k_gx<<<dim3(32, 16), 256, 0, stream>>>(feat, Wihp, Wih, bih, bhh, act, gx);
    k_lstm_all<<<32, 1024, 0, stream>>>(h0, c0, done, gx, Wq, amax, hs, cb);
    k_heads<<<256, 256, 0, stream>>>(hs, cb, Wp1, bp1, Wp2, bp2, Wv1, bv1, Wv2, bv2, out);
}